// Round 13
// baseline (81.998 us; speedup 1.0000x reference)
//
#include <hip/hip_runtime.h>
#include <math.h>

#define Bn 256
#define Dm 256
#define Hm 512
#define Em 64
#define NL 1024
#define TOPK 10
#define GS 8          // samples per expert group
#define MAXG 88       // max groups: 64 + (256-64)/8

// ---------- distributed routing preamble ----------
// Each block recomputes the (deterministic) routing from idx[256]:
//   histogram -> dual prefix scan -> this block's group (e, k, p0, cnt)
//   optional: row list srow[c] = (k*GS+c)-th sample with idx==e (rank by ascending index).
// shm layout (ints): cnt[64] | offs[64] | wtot[4] | sel[2]
__device__ __forceinline__ void route_group(const int* __restrict__ idx, int g,
        int tid, int* shm, int* srow, bool need_rows,
        int& e_out, int& p0_out, int& cnt_out) {
    int* cnt  = shm;
    int* offs = shm + 64;
    int* wtot = shm + 128;
    int* sel  = shm + 132;
    if (tid < Em) cnt[tid] = 0;
    if (tid == 0) { sel[0] = -1; sel[1] = 0; }
    __syncthreads();
    int myE = -1;
    if (tid < Bn) { myE = idx[tid]; atomicAdd(&cnt[myE], 1); }
    __syncthreads();
    if (tid < Em) {   // wave 0: dual inclusive scan (samples, groups)
        const int n  = cnt[tid];
        const int ng = (n + GS - 1) / GS;
        int s1 = n, s2 = ng;
        #pragma unroll
        for (int off = 1; off < 64; off <<= 1) {
            const int t1 = __shfl_up(s1, off);
            const int t2 = __shfl_up(s2, off);
            if (tid >= off) { s1 += t1; s2 += t2; }
        }
        offs[tid] = s1 - n;
        if (n > 0 && g >= s2 - ng && g < s2) { sel[0] = tid; sel[1] = g - (s2 - ng); }
    }
    __syncthreads();
    const int e = sel[0];
    if (e < 0) { e_out = -1; return; }
    const int k = sel[1];
    const int n = cnt[e];
    e_out = e;
    p0_out = offs[e] + k * GS;
    cnt_out = min(GS, n - k * GS);
    if (need_rows) {
        const int wave = tid >> 6, lane = tid & 63;
        const bool match = (tid < Bn) && (myE == e);
        const unsigned long long m = __ballot(match ? 1 : 0);
        if (wave < 4 && lane == 0) wtot[wave] = (int)__popcll(m);
        __syncthreads();
        if (match) {
            int woff = 0;
            for (int w = 0; w < wave; ++w) woff += wtot[w];
            const int rank = woff + (int)__popcll(m & ((1ull << lane) - 1ull));
            const int s = rank - k * GS;
            if (s >= 0 && s < GS) srow[s] = tid;
        }
        __syncthreads();
    }
}

// For topk: global position p -> (expert e, original sample b)
__device__ __forceinline__ void route_sample(const int* __restrict__ idx, int p,
        int tid, int* shm, int& e_out, int& b_out) {
    int* cnt  = shm;
    int* offs = shm + 64;
    int* wtot = shm + 128;
    int* sel  = shm + 132;   // [e, r, b]
    if (tid < Em) cnt[tid] = 0;
    __syncthreads();
    int myE = -1;
    if (tid < Bn) { myE = idx[tid]; atomicAdd(&cnt[myE], 1); }
    __syncthreads();
    if (tid < Em) {
        const int n = cnt[tid];
        int s1 = n;
        #pragma unroll
        for (int off = 1; off < 64; off <<= 1) {
            const int t1 = __shfl_up(s1, off);
            if (tid >= off) s1 += t1;
        }
        offs[tid] = s1 - n;
        if (n > 0 && p >= s1 - n && p < s1) { sel[0] = tid; sel[1] = p - (s1 - n); }
    }
    __syncthreads();
    const int e = sel[0];
    const int r = sel[1];
    {
        const int wave = tid >> 6, lane = tid & 63;
        const bool match = (tid < Bn) && (myE == e);
        const unsigned long long m = __ballot(match ? 1 : 0);
        if (wave < 4 && lane == 0) wtot[wave] = (int)__popcll(m);
        __syncthreads();
        if (match) {
            int woff = 0;
            for (int w = 0; w < wave; ++w) woff += wtot[w];
            const int rank = woff + (int)__popcll(m & ((1ull << lane) - 1ull));
            if (rank == r) sel[2] = tid;
        }
        __syncthreads();
    }
    e_out = e;
    b_out = sel[2];
}

// ============ K-split dense: blockIdx.z = K-part -> writes its OWN buffer ============
// MODE 0: ungrouped (root). MODE 1: grouped, gather input rows via srow (expert L1).
// MODE 2: grouped, positional input (expert L2/L3). Y part buffers contiguous.
template<int IN, int OUT, int MT, int XPARTS, int KSPLIT, int MODE>
__global__ __launch_bounds__(512) void dense_ks(
        const float* __restrict__ X, const int* __restrict__ idx,
        const float* __restrict__ Bin, int bin_estride,
        const float* __restrict__ W, float* __restrict__ Y) {
    constexpr int NW = 8, KQ = IN / KSPLIT, KCH = KQ / NW, CCH = 256, NR = 4;

    __shared__ float sxT[KQ * MT];      // [local i][c]
    __shared__ float part[NR * MT * CCH];
    __shared__ int rshm[136];
    __shared__ int srow[GS];
    const int tid = threadIdx.x;

    int e, p0, cnt;
    if (MODE != 0) {
        route_group(idx, blockIdx.x, tid, rshm, srow, MODE == 1, e, p0, cnt);
        if (e < 0) return;
    } else {
        e = 0; p0 = blockIdx.x * MT; cnt = MT;
    }
    const int kq = blockIdx.z;          // 0..KSPLIT-1
    const int kbase = kq * KQ;

    // stage activations (sum XPARTS part-buffers; bias+relu of previous layer)
    for (int j = tid; j < (KQ / 4) * MT; j += 512) {
        const int c  = j & (MT - 1);
        const int i4 = j / MT;
        float4 x = make_float4(0.f, 0.f, 0.f, 0.f);
        if (c < cnt) {
            const int row = (MODE == 1) ? srow[c] : (p0 + c);
            const size_t off = (size_t)row * IN + kbase + i4 * 4;
            x = *(const float4*)(X + off);
            #pragma unroll
            for (int pb = 1; pb < XPARTS; ++pb) {
                const float4 xp = *(const float4*)(X + (size_t)pb * Bn * IN + off);
                x.x += xp.x; x.y += xp.y; x.z += xp.z; x.w += xp.w;
            }
            if (Bin) {
                const float4 b = *(const float4*)(Bin + (size_t)e * bin_estride + kbase + i4 * 4);
                x.x = fmaxf(x.x + b.x, 0.f); x.y = fmaxf(x.y + b.y, 0.f);
                x.z = fmaxf(x.z + b.z, 0.f); x.w = fmaxf(x.w + b.w, 0.f);
            }
        }
        sxT[(i4 * 4 + 0) * MT + c] = x.x;
        sxT[(i4 * 4 + 1) * MT + c] = x.y;
        sxT[(i4 * 4 + 2) * MT + c] = x.z;
        sxT[(i4 * 4 + 3) * MT + c] = x.w;
    }
    __syncthreads();

    const int wave = tid >> 6, lane = tid & 63;
    const int colb = blockIdx.y * CCH;
    const int col  = colb + lane * 4;
    const int k0   = wave * KCH;
    const float* We = W + (size_t)e * IN * OUT + (size_t)(kbase + k0) * OUT + col;

    float acc[MT][4];
    #pragma unroll
    for (int c = 0; c < MT; ++c) { acc[c][0]=0.f; acc[c][1]=0.f; acc[c][2]=0.f; acc[c][3]=0.f; }

    #pragma unroll 4
    for (int i = 0; i < KCH; ++i) {
        const float4 w = *(const float4*)(We + (size_t)i * OUT);
        const float* xr = &sxT[(k0 + i) * MT];
        const float4 xa = *(const float4*)xr;
        const float4 xb = *(const float4*)(xr + 4);
        const float xs[8] = {xa.x, xa.y, xa.z, xa.w, xb.x, xb.y, xb.z, xb.w};
        #pragma unroll
        for (int c = 0; c < 8; ++c) {
            acc[c][0] = fmaf(xs[c], w.x, acc[c][0]);
            acc[c][1] = fmaf(xs[c], w.y, acc[c][1]);
            acc[c][2] = fmaf(xs[c], w.z, acc[c][2]);
            acc[c][3] = fmaf(xs[c], w.w, acc[c][3]);
        }
    }

    // LDS partial reduce: waves 0-3 write, 4-7 fold
    if (wave < NR) {
        #pragma unroll
        for (int c = 0; c < MT; ++c)
            *(float4*)&part[((wave * MT) + c) * CCH + lane * 4] = *(const float4*)acc[c];
    }
    __syncthreads();
    if (wave >= NR) {
        #pragma unroll
        for (int c = 0; c < MT; ++c) {
            float4* pp = (float4*)&part[(((wave - NR) * MT) + c) * CCH + lane * 4];
            float4 v = *pp;
            v.x += acc[c][0]; v.y += acc[c][1]; v.z += acc[c][2]; v.w += acc[c][3];
            *pp = v;
        }
    }
    __syncthreads();

    // final in-block reduce over 4 slots -> direct store into this part's buffer
    float* Yq = Y + (size_t)kq * Bn * OUT;
    for (int j = tid; j < MT * (CCH / 4); j += 512) {
        const int c = j / (CCH / 4);
        const int q = j % (CCH / 4);
        float4 s = *(const float4*)&part[c * CCH + q * 4];
        #pragma unroll
        for (int w = 1; w < NR; ++w) {
            const float4 p2 = *(const float4*)&part[((w * MT) + c) * CCH + q * 4];
            s.x += p2.x; s.y += p2.y; s.z += p2.z; s.w += p2.w;
        }
        if (c < cnt)
            *(float4*)(Yq + (size_t)(p0 + c) * OUT + colb + q * 4) = s;
    }
}

// ============ root L3 (512 -> 64) + argmax + log-softmax-at-argmax ============
__global__ __launch_bounds__(512) void root3_ks(
        const float* __restrict__ H2, const float* __restrict__ Bin,
        const float* __restrict__ W, const float* __restrict__ bias,
        int* __restrict__ idx_out, float* __restrict__ rlp_out) {
    __shared__ float sxT[Hm * 8];
    __shared__ float part[8 * 8 * Em];
    __shared__ float fin[8][Em];
    const int tid = threadIdx.x;
    const int b0 = blockIdx.x * 8;

    for (int j = tid; j < (Hm / 4) * 8; j += 512) {
        const int c = j & 7, i4 = j >> 3;
        const size_t off = (size_t)(b0 + c) * Hm + i4 * 4;
        float4 x = *(const float4*)(H2 + off);
        #pragma unroll
        for (int pb = 1; pb < 4; ++pb) {
            const float4 xp = *(const float4*)(H2 + (size_t)pb * Bn * Hm + off);
            x.x += xp.x; x.y += xp.y; x.z += xp.z; x.w += xp.w;
        }
        const float4 b = *(const float4*)(Bin + i4 * 4);
        x.x = fmaxf(x.x + b.x, 0.f); x.y = fmaxf(x.y + b.y, 0.f);
        x.z = fmaxf(x.z + b.z, 0.f); x.w = fmaxf(x.w + b.w, 0.f);
        sxT[(i4 * 4 + 0) * 8 + c] = x.x;
        sxT[(i4 * 4 + 1) * 8 + c] = x.y;
        sxT[(i4 * 4 + 2) * 8 + c] = x.z;
        sxT[(i4 * 4 + 3) * 8 + c] = x.w;
    }
    __syncthreads();

    const int wave = tid >> 6, lane = tid & 63;
    const int k0 = wave * 64;
    float acc[8] = {0.f,0.f,0.f,0.f,0.f,0.f,0.f,0.f};
    #pragma unroll 4
    for (int i = 0; i < 64; ++i) {
        const float w = W[(size_t)(k0 + i) * Em + lane];
        const float* xr = &sxT[(k0 + i) * 8];
        const float4 xa = *(const float4*)xr;
        const float4 xb = *(const float4*)(xr + 4);
        acc[0] = fmaf(xa.x, w, acc[0]); acc[1] = fmaf(xa.y, w, acc[1]);
        acc[2] = fmaf(xa.z, w, acc[2]); acc[3] = fmaf(xa.w, w, acc[3]);
        acc[4] = fmaf(xb.x, w, acc[4]); acc[5] = fmaf(xb.y, w, acc[5]);
        acc[6] = fmaf(xb.z, w, acc[6]); acc[7] = fmaf(xb.w, w, acc[7]);
    }
    #pragma unroll
    for (int c = 0; c < 8; ++c) part[(wave * 8 + c) * Em + lane] = acc[c];
    __syncthreads();
    {   // 512 threads = 8 samples x 64 cols
        const int c = wave, colj = lane;
        float s = bias[colj];
        #pragma unroll
        for (int w = 0; w < 8; ++w) s += part[(w * 8 + c) * Em + colj];
        fin[c][colj] = s;
    }
    __syncthreads();
    {   // wave c handles sample c: argmax (tie -> smaller idx) + lse
        const int c = wave;
        const float a0 = fin[c][lane];
        float v = a0; int bi = lane;
        #pragma unroll
        for (int off = 32; off; off >>= 1) {
            const float ov = __shfl_xor(v, off);
            const int   oi = __shfl_xor(bi, off);
            if (ov > v || (ov == v && oi < bi)) { v = ov; bi = oi; }
        }
        float ssum = expf(a0 - v);
        #pragma unroll
        for (int off = 32; off; off >>= 1) ssum += __shfl_xor(ssum, off);
        if (lane == 0) { idx_out[b0 + c] = bi; rlp_out[b0 + c] = -logf(ssum); }
    }
}

// ============ log-softmax + top-11 + filter + outputs (2 logit halves + eb3) ============
__global__ __launch_bounds__(512) void topk_kernel(
        const float* __restrict__ logitsQ, const float* __restrict__ eb3,
        const int* __restrict__ idx, const float* __restrict__ rlp,
        float* __restrict__ out) {
    __shared__ float sl[NL];
    __shared__ float redA[8];
    __shared__ float redB[8];
    __shared__ float bcast[2];
    __shared__ int rshm[136];
    const int p = blockIdx.x;
    const int tid = threadIdx.x;

    int e, b;
    route_sample(idx, p, tid, rshm, e, b);

    const size_t off = (size_t)p * NL + tid * 2;
    float2 v2 = *(const float2*)(logitsQ + off);
    {
        const float2 vp = *(const float2*)(logitsQ + (size_t)Bn * NL + off);
        v2.x += vp.x; v2.y += vp.y;
    }
    const float2 b2 = *(const float2*)(eb3 + (size_t)e * NL + tid * 2);
    v2.x += b2.x; v2.y += b2.y;
    sl[tid * 2] = v2.x; sl[tid * 2 + 1] = v2.y;

    float m = fmaxf(v2.x, v2.y);
    #pragma unroll
    for (int off2 = 32; off2; off2 >>= 1) m = fmaxf(m, __shfl_xor(m, off2));
    const int wave = tid >> 6;
    if ((tid & 63) == 0) redA[wave] = m;
    __syncthreads();
    if (tid == 0) {
        float mm = redA[0];
        #pragma unroll
        for (int w = 1; w < 8; ++w) mm = fmaxf(mm, redA[w]);
        bcast[0] = mm;
    }
    __syncthreads();
    m = bcast[0];

    float s = expf(v2.x - m) + expf(v2.y - m);
    #pragma unroll
    for (int off2 = 32; off2; off2 >>= 1) s += __shfl_xor(s, off2);
    if ((tid & 63) == 0) redB[wave] = s;
    __syncthreads();
    if (tid == 0) {
        float ss = 0.f;
        #pragma unroll
        for (int w = 0; w < 8; ++w) ss += redB[w];
        bcast[1] = m + logf(ss);
    }
    __syncthreads();
    const float logZ = bcast[1];

    if (tid < 64) {
        float vals[16];
        #pragma unroll
        for (int q = 0; q < 16; ++q) vals[q] = sl[tid * 16 + q];
        float selv[11];
        int   seli[11];
        for (int t = 0; t < 11; ++t) {
            float v = -INFINITY; int bq = 0;
            #pragma unroll
            for (int q = 0; q < 16; ++q) {
                if (vals[q] > v) { v = vals[q]; bq = q; }  // first occurrence on ties
            }
            int gi = tid * 16 + bq;
            #pragma unroll
            for (int off2 = 32; off2; off2 >>= 1) {
                const float ov = __shfl_xor(v, off2);
                const int   oi = __shfl_xor(gi, off2);
                if (ov > v || (ov == v && oi < gi)) { v = ov; gi = oi; }
            }
            selv[t] = v;
            seli[t] = gi;
            if ((gi >> 4) == tid) vals[gi & 15] = -INFINITY;
        }
        if (tid == 0) {
            const float rl = rlp[b];
            int c2 = 0;
            for (int t = 0; t < 11 && c2 < TOPK; ++t) {
                if (seli[t] == 0 && e == 0) continue;  // drop the (0,0) trajectory
                out[(b * TOPK + c2) * 2 + 0] = (float)e;
                out[(b * TOPK + c2) * 2 + 1] = (float)seli[t];
                out[Bn * TOPK * 2 + b * TOPK + c2] = selv[t] - logZ + rl;
                ++c2;
            }
        }
    }
}

extern "C" void kernel_launch(void* const* d_in, const int* in_sizes, int n_in,
                              void* d_out, int out_size, void* d_ws, size_t ws_size,
                              hipStream_t stream) {
    const float* state = (const float*)d_in[0];
    const float* rW1   = (const float*)d_in[1];
    const float* rb1   = (const float*)d_in[2];
    const float* rW2   = (const float*)d_in[3];
    const float* rb2   = (const float*)d_in[4];
    const float* rW3   = (const float*)d_in[5];
    const float* rb3   = (const float*)d_in[6];
    const float* eW1   = (const float*)d_in[7];
    const float* eb1   = (const float*)d_in[8];
    const float* eW2   = (const float*)d_in[9];
    const float* eb2   = (const float*)d_in[10];
    const float* eW3   = (const float*)d_in[11];
    const float* eb3   = (const float*)d_in[12];
    float* out = (float*)d_out;

    // part-sum buffers (contiguous parts), then control
    float* h1p    = (float*)d_ws;            // 4 x [256][512] root L1 quarters
    float* h2p    = h1p + 4 * Bn * Hm;       // 4 x [256][512] root L2 quarters
    float* eh1p   = h2p + 4 * Bn * Hm;       // 4 x [256][512] expert L1 quarters (permuted)
    float* eh2p   = eh1p + 4 * Bn * Hm;      // 4 x [256][512] expert L2 quarters (permuted)
    float* logp   = eh2p + 4 * Bn * Hm;      // 2 x [256][1024] expert L3 halves (permuted)
    float* rlp    = logp + 2 * Bn * NL;      // [256]
    int*   idxp   = (int*)(rlp + Bn);        // [256]

    dense_ks<Dm, Hm, 8, 1, 4, 0><<<dim3(Bn / 8, Hm / 256, 4), 512, 0, stream>>>(
        state, nullptr, nullptr, 0, rW1, h1p);
    dense_ks<Hm, Hm, 8, 4, 4, 0><<<dim3(Bn / 8, Hm / 256, 4), 512, 0, stream>>>(
        h1p, nullptr, rb1, 0, rW2, h2p);
    root3_ks<<<Bn / 8, 512, 0, stream>>>(h2p, rb2, rW3, rb3, idxp, rlp);
    dense_ks<Dm, Hm, 8, 1, 4, 1><<<dim3(MAXG, Hm / 256, 4), 512, 0, stream>>>(
        state, idxp, nullptr, 0, eW1, eh1p);
    dense_ks<Hm, Hm, 8, 4, 4, 2><<<dim3(MAXG, Hm / 256, 4), 512, 0, stream>>>(
        eh1p, idxp, eb1, Hm, eW2, eh2p);
    dense_ks<Hm, NL, 8, 4, 2, 2><<<dim3(MAXG, NL / 256, 2), 512, 0, stream>>>(
        eh2p, idxp, eb2, Hm, eW3, logp);
    topk_kernel<<<Bn, 512, 0, stream>>>(logp, eb3, idxp, rlp, out);
}

// Round 14
// 80.633 us; speedup vs baseline: 1.0169x; 1.0169x over previous
//
#include <hip/hip_runtime.h>
#include <math.h>

#define Bn 256
#define Dm 256
#define Hm 512
#define Em 64
#define NL 1024
#define TOPK 10
#define GS 8          // samples per expert group
#define MAXG 88       // max groups: 64 + (256-64)/8

// ============ K-split dense: blockIdx.z = K-part -> writes its OWN buffer ============
// Y part buffers contiguous: Y + kq*Bn*OUT. Consumers add the KSPLIT parts.
// Input X has XPARTS part-buffers (stride Bn*IN) added at staging, with optional
// bias+relu of the previous layer (Bin != nullptr).
template<int IN, int OUT, int MT, int XPARTS, bool GROUPED, int KSPLIT>
__global__ __launch_bounds__(512) void dense_ks(
        const float* __restrict__ X, const int* __restrict__ perm,
        const float* __restrict__ Bin, int bin_estride,
        const float* __restrict__ W, const int4* __restrict__ groups,
        float* __restrict__ Y) {
    constexpr int NW = 8, KQ = IN / KSPLIT, KCH = KQ / NW, CCH = 256, NR = 4;

    int e, p0, cnt;
    if (GROUPED) {
        const int4 g = groups[blockIdx.x];
        if (g.z == 0) return;
        e = g.x; p0 = g.y; cnt = g.z;
    } else {
        e = 0; p0 = blockIdx.x * MT; cnt = MT;
    }
    const int kq = blockIdx.z;          // 0..KSPLIT-1
    const int kbase = kq * KQ;

    __shared__ float sxT[KQ * MT];      // [local i][c]
    __shared__ float part[NR * MT * CCH];
    const int tid = threadIdx.x;

    // stage activations (sum XPARTS part-buffers; bias+relu of previous layer)
    for (int j = tid; j < (KQ / 4) * MT; j += 512) {
        const int c  = j & (MT - 1);
        const int i4 = j / MT;
        float4 x = make_float4(0.f, 0.f, 0.f, 0.f);
        if (c < cnt) {
            const int row = perm ? perm[p0 + c] : (p0 + c);
            const size_t off = (size_t)row * IN + kbase + i4 * 4;
            x = *(const float4*)(X + off);
            #pragma unroll
            for (int pb = 1; pb < XPARTS; ++pb) {
                const float4 xp = *(const float4*)(X + (size_t)pb * Bn * IN + off);
                x.x += xp.x; x.y += xp.y; x.z += xp.z; x.w += xp.w;
            }
            if (Bin) {
                const float4 b = *(const float4*)(Bin + (size_t)e * bin_estride + kbase + i4 * 4);
                x.x = fmaxf(x.x + b.x, 0.f); x.y = fmaxf(x.y + b.y, 0.f);
                x.z = fmaxf(x.z + b.z, 0.f); x.w = fmaxf(x.w + b.w, 0.f);
            }
        }
        sxT[(i4 * 4 + 0) * MT + c] = x.x;
        sxT[(i4 * 4 + 1) * MT + c] = x.y;
        sxT[(i4 * 4 + 2) * MT + c] = x.z;
        sxT[(i4 * 4 + 3) * MT + c] = x.w;
    }
    __syncthreads();

    const int wave = tid >> 6, lane = tid & 63;
    const int colb = blockIdx.y * CCH;
    const int col  = colb + lane * 4;
    const int k0   = wave * KCH;
    const float* We = W + (size_t)e * IN * OUT + (size_t)(kbase + k0) * OUT + col;

    float acc[MT][4];
    #pragma unroll
    for (int c = 0; c < MT; ++c) { acc[c][0]=0.f; acc[c][1]=0.f; acc[c][2]=0.f; acc[c][3]=0.f; }

    #pragma unroll 4
    for (int i = 0; i < KCH; ++i) {
        const float4 w = *(const float4*)(We + (size_t)i * OUT);
        const float* xr = &sxT[(k0 + i) * MT];
        const float4 xa = *(const float4*)xr;
        const float4 xb = *(const float4*)(xr + 4);
        const float xs[8] = {xa.x, xa.y, xa.z, xa.w, xb.x, xb.y, xb.z, xb.w};
        #pragma unroll
        for (int c = 0; c < 8; ++c) {
            acc[c][0] = fmaf(xs[c], w.x, acc[c][0]);
            acc[c][1] = fmaf(xs[c], w.y, acc[c][1]);
            acc[c][2] = fmaf(xs[c], w.z, acc[c][2]);
            acc[c][3] = fmaf(xs[c], w.w, acc[c][3]);
        }
    }

    // LDS partial reduce: waves 0-3 write, 4-7 fold
    if (wave < NR) {
        #pragma unroll
        for (int c = 0; c < MT; ++c)
            *(float4*)&part[((wave * MT) + c) * CCH + lane * 4] = *(const float4*)acc[c];
    }
    __syncthreads();
    if (wave >= NR) {
        #pragma unroll
        for (int c = 0; c < MT; ++c) {
            float4* pp = (float4*)&part[(((wave - NR) * MT) + c) * CCH + lane * 4];
            float4 v = *pp;
            v.x += acc[c][0]; v.y += acc[c][1]; v.z += acc[c][2]; v.w += acc[c][3];
            *pp = v;
        }
    }
    __syncthreads();

    // final in-block reduce over 4 slots -> direct store into this part's buffer
    float* Yq = Y + (size_t)kq * Bn * OUT;
    for (int j = tid; j < MT * (CCH / 4); j += 512) {
        const int c = j / (CCH / 4);
        const int q = j % (CCH / 4);
        float4 s = *(const float4*)&part[c * CCH + q * 4];
        #pragma unroll
        for (int w = 1; w < NR; ++w) {
            const float4 p2 = *(const float4*)&part[((w * MT) + c) * CCH + q * 4];
            s.x += p2.x; s.y += p2.y; s.z += p2.z; s.w += p2.w;
        }
        if (c < cnt)
            *(float4*)(Yq + (size_t)(p0 + c) * OUT + colb + q * 4) = s;
    }
}

// ============ root L3 (512 -> 64) + argmax + log-softmax-at-argmax ============
// Input = h2 quarter-sums (4 parts); rb2+relu applied at staging.
__global__ __launch_bounds__(512) void root3_ks(
        const float* __restrict__ H2, const float* __restrict__ Bin,
        const float* __restrict__ W, const float* __restrict__ bias,
        int* __restrict__ idx_out, float* __restrict__ rlp_out) {
    __shared__ float sxT[Hm * 8];
    __shared__ float part[8 * 8 * Em];
    __shared__ float fin[8][Em];
    const int tid = threadIdx.x;
    const int b0 = blockIdx.x * 8;

    for (int j = tid; j < (Hm / 4) * 8; j += 512) {
        const int c = j & 7, i4 = j >> 3;
        const size_t off = (size_t)(b0 + c) * Hm + i4 * 4;
        float4 x = *(const float4*)(H2 + off);
        #pragma unroll
        for (int pb = 1; pb < 4; ++pb) {
            const float4 xp = *(const float4*)(H2 + (size_t)pb * Bn * Hm + off);
            x.x += xp.x; x.y += xp.y; x.z += xp.z; x.w += xp.w;
        }
        const float4 b = *(const float4*)(Bin + i4 * 4);
        x.x = fmaxf(x.x + b.x, 0.f); x.y = fmaxf(x.y + b.y, 0.f);
        x.z = fmaxf(x.z + b.z, 0.f); x.w = fmaxf(x.w + b.w, 0.f);
        sxT[(i4 * 4 + 0) * 8 + c] = x.x;
        sxT[(i4 * 4 + 1) * 8 + c] = x.y;
        sxT[(i4 * 4 + 2) * 8 + c] = x.z;
        sxT[(i4 * 4 + 3) * 8 + c] = x.w;
    }
    __syncthreads();

    const int wave = tid >> 6, lane = tid & 63;
    const int k0 = wave * 64;
    float acc[8] = {0.f,0.f,0.f,0.f,0.f,0.f,0.f,0.f};
    #pragma unroll 4
    for (int i = 0; i < 64; ++i) {
        const float w = W[(size_t)(k0 + i) * Em + lane];
        const float* xr = &sxT[(k0 + i) * 8];
        const float4 xa = *(const float4*)xr;
        const float4 xb = *(const float4*)(xr + 4);
        acc[0] = fmaf(xa.x, w, acc[0]); acc[1] = fmaf(xa.y, w, acc[1]);
        acc[2] = fmaf(xa.z, w, acc[2]); acc[3] = fmaf(xa.w, w, acc[3]);
        acc[4] = fmaf(xb.x, w, acc[4]); acc[5] = fmaf(xb.y, w, acc[5]);
        acc[6] = fmaf(xb.z, w, acc[6]); acc[7] = fmaf(xb.w, w, acc[7]);
    }
    #pragma unroll
    for (int c = 0; c < 8; ++c) part[(wave * 8 + c) * Em + lane] = acc[c];
    __syncthreads();
    {   // 512 threads = 8 samples x 64 cols
        const int c = wave, colj = lane;
        float s = bias[colj];
        #pragma unroll
        for (int w = 0; w < 8; ++w) s += part[(w * 8 + c) * Em + colj];
        fin[c][colj] = s;
    }
    __syncthreads();
    {   // wave c handles sample c: argmax (tie -> smaller idx) + lse
        const int c = wave;
        const float a0 = fin[c][lane];
        float v = a0; int bi = lane;
        #pragma unroll
        for (int off = 32; off; off >>= 1) {
            const float ov = __shfl_xor(v, off);
            const int   oi = __shfl_xor(bi, off);
            if (ov > v || (ov == v && oi < bi)) { v = ov; bi = oi; }
        }
        float ssum = expf(a0 - v);
        #pragma unroll
        for (int off = 32; off; off >>= 1) ssum += __shfl_xor(ssum, off);
        if (lane == 0) { idx_out[b0 + c] = bi; rlp_out[b0 + c] = -logf(ssum); }
    }
}

// ============ routing: parallel prefix-scan + per-lane group emission ============
__global__ __launch_bounds__(256) void routing_kernel(const int* __restrict__ idx,
        int* __restrict__ perm, int4* __restrict__ groups) {
    __shared__ int cnt[Em];
    __shared__ int offs[Em];
    __shared__ int gtot;
    const int tid = threadIdx.x;  // 256 threads
    if (tid < Em) cnt[tid] = 0;
    __syncthreads();
    const int e = idx[tid];
    const int r = atomicAdd(&cnt[e], 1);
    __syncthreads();
    if (tid < Em) {   // wave 0: dual inclusive scan (samples, groups) over 64 lanes
        const int n  = cnt[tid];
        const int ng = (n + GS - 1) / GS;
        int s1 = n, s2 = ng;
        #pragma unroll
        for (int off = 1; off < 64; off <<= 1) {
            const int t1 = __shfl_up(s1, off);
            const int t2 = __shfl_up(s2, off);
            if (tid >= off) { s1 += t1; s2 += t2; }
        }
        offs[tid] = s1 - n;            // exclusive sample offset
        if (tid == Em - 1) gtot = s2;
        const int gb = s2 - ng;        // exclusive group offset
        for (int k = 0; k < ng; ++k)
            groups[gb + k] = make_int4(tid, (s1 - n) + k * GS, min(GS, n - k * GS), 0);
    }
    __syncthreads();
    for (int g = gtot + tid; g < MAXG; g += 256) groups[g] = make_int4(0, 0, 0, 0);
    perm[offs[e] + r] = tid;
}

// ============ log-softmax + top-11 + filter + outputs (2 logit halves + eb3) ============
__global__ __launch_bounds__(512) void topk_kernel(
        const float* __restrict__ logitsQ, const float* __restrict__ eb3,
        const int* __restrict__ perm, const int* __restrict__ idx,
        const float* __restrict__ rlp, float* __restrict__ out) {
    __shared__ float sl[NL];
    __shared__ float redA[8];
    __shared__ float redB[8];
    __shared__ float bcast[2];
    const int p = blockIdx.x;
    const int tid = threadIdx.x;
    const int b = perm[p];
    const int e = idx[b];

    const size_t off = (size_t)p * NL + tid * 2;
    float2 v2 = *(const float2*)(logitsQ + off);
    {
        const float2 vp = *(const float2*)(logitsQ + (size_t)Bn * NL + off);
        v2.x += vp.x; v2.y += vp.y;
    }
    const float2 b2 = *(const float2*)(eb3 + (size_t)e * NL + tid * 2);
    v2.x += b2.x; v2.y += b2.y;
    sl[tid * 2] = v2.x; sl[tid * 2 + 1] = v2.y;

    float m = fmaxf(v2.x, v2.y);
    #pragma unroll
    for (int off2 = 32; off2; off2 >>= 1) m = fmaxf(m, __shfl_xor(m, off2));
    const int wave = tid >> 6;
    if ((tid & 63) == 0) redA[wave] = m;
    __syncthreads();
    if (tid == 0) {
        float mm = redA[0];
        #pragma unroll
        for (int w = 1; w < 8; ++w) mm = fmaxf(mm, redA[w]);
        bcast[0] = mm;
    }
    __syncthreads();
    m = bcast[0];

    float s = expf(v2.x - m) + expf(v2.y - m);
    #pragma unroll
    for (int off2 = 32; off2; off2 >>= 1) s += __shfl_xor(s, off2);
    if ((tid & 63) == 0) redB[wave] = s;
    __syncthreads();
    if (tid == 0) {
        float ss = 0.f;
        #pragma unroll
        for (int w = 0; w < 8; ++w) ss += redB[w];
        bcast[1] = m + logf(ss);
    }
    __syncthreads();
    const float logZ = bcast[1];

    if (tid < 64) {
        float vals[16];
        #pragma unroll
        for (int q = 0; q < 16; ++q) vals[q] = sl[tid * 16 + q];
        float selv[11];
        int   seli[11];
        for (int t = 0; t < 11; ++t) {
            float v = -INFINITY; int bq = 0;
            #pragma unroll
            for (int q = 0; q < 16; ++q) {
                if (vals[q] > v) { v = vals[q]; bq = q; }  // first occurrence on ties
            }
            int gi = tid * 16 + bq;
            #pragma unroll
            for (int off2 = 32; off2; off2 >>= 1) {
                const float ov = __shfl_xor(v, off2);
                const int   oi = __shfl_xor(gi, off2);
                if (ov > v || (ov == v && oi < gi)) { v = ov; gi = oi; }
            }
            selv[t] = v;
            seli[t] = gi;
            if ((gi >> 4) == tid) vals[gi & 15] = -INFINITY;
        }
        if (tid == 0) {
            const float rl = rlp[b];
            int c2 = 0;
            for (int t = 0; t < 11 && c2 < TOPK; ++t) {
                if (seli[t] == 0 && e == 0) continue;  // drop the (0,0) trajectory
                out[(b * TOPK + c2) * 2 + 0] = (float)e;
                out[(b * TOPK + c2) * 2 + 1] = (float)seli[t];
                out[Bn * TOPK * 2 + b * TOPK + c2] = selv[t] - logZ + rl;
                ++c2;
            }
        }
    }
}

extern "C" void kernel_launch(void* const* d_in, const int* in_sizes, int n_in,
                              void* d_out, int out_size, void* d_ws, size_t ws_size,
                              hipStream_t stream) {
    const float* state = (const float*)d_in[0];
    const float* rW1   = (const float*)d_in[1];
    const float* rb1   = (const float*)d_in[2];
    const float* rW2   = (const float*)d_in[3];
    const float* rb2   = (const float*)d_in[4];
    const float* rW3   = (const float*)d_in[5];
    const float* rb3   = (const float*)d_in[6];
    const float* eW1   = (const float*)d_in[7];
    const float* eb1   = (const float*)d_in[8];
    const float* eW2   = (const float*)d_in[9];
    const float* eb2   = (const float*)d_in[10];
    const float* eW3   = (const float*)d_in[11];
    const float* eb3   = (const float*)d_in[12];
    float* out = (float*)d_out;

    // part-sum buffers (contiguous parts), then control
    float* h1p    = (float*)d_ws;            // 4 x [256][512] root L1 quarters
    float* h2p    = h1p + 4 * Bn * Hm;       // 4 x [256][512] root L2 quarters
    float* eh1p   = h2p + 4 * Bn * Hm;       // 4 x [256][512] expert L1 quarters (permuted)
    float* eh2p   = eh1p + 4 * Bn * Hm;      // 4 x [256][512] expert L2 quarters (permuted)
    float* logp   = eh2p + 4 * Bn * Hm;      // 2 x [256][1024] expert L3 halves (permuted)
    float* rlp    = logp + 2 * Bn * NL;      // [256]
    int*   idxp   = (int*)(rlp + Bn);        // [256]
    int*   perm   = idxp + Bn;               // [256]
    int4*  groups = (int4*)(perm + Bn);      // [88]

    dense_ks<Dm, Hm, 8, 1, false, 4><<<dim3(Bn / 8, Hm / 256, 4), 512, 0, stream>>>(
        state, nullptr, nullptr, 0, rW1, nullptr, h1p);
    dense_ks<Hm, Hm, 8, 4, false, 4><<<dim3(Bn / 8, Hm / 256, 4), 512, 0, stream>>>(
        h1p, nullptr, rb1, 0, rW2, nullptr, h2p);
    root3_ks<<<Bn / 8, 512, 0, stream>>>(h2p, rb2, rW3, rb3, idxp, rlp);
    routing_kernel<<<1, 256, 0, stream>>>(idxp, perm, groups);
    dense_ks<Dm, Hm, 8, 1, true, 4><<<dim3(MAXG, Hm / 256, 4), 512, 0, stream>>>(
        state, perm, nullptr, 0, eW1, groups, eh1p);
    dense_ks<Hm, Hm, 8, 4, true, 4><<<dim3(MAXG, Hm / 256, 4), 512, 0, stream>>>(
        eh1p, nullptr, eb1, Hm, eW2, groups, eh2p);
    dense_ks<Hm, NL, 8, 4, true, 2><<<dim3(MAXG, NL / 256, 2), 512, 0, stream>>>(
        eh2p, nullptr, eb2, Hm, eW3, groups, logp);
    topk_kernel<<<Bn, 512, 0, stream>>>(logp, eb3, perm, idxp, rlp, out);
}